// Round 1
// 826.310 us; speedup vs baseline: 1.0122x; 1.0122x over previous
//
#include <hip/hip_runtime.h>

#define QLEN 1024
#define KLEN 2048
#define BSZ 4
#define NHEAD 16
#define DHEAD 64
#define DMODEL 1024
#define RP1 2049  // KLEN + 1

typedef short short8 __attribute__((ext_vector_type(8)));
typedef short short4v __attribute__((ext_vector_type(4)));
typedef float float4v __attribute__((ext_vector_type(4)));

__device__ inline float bf2f(unsigned short u) {
    union { unsigned int i; float f; } v; v.i = ((unsigned int)u) << 16; return v.f;
}
__device__ inline unsigned short f2bf(float f) {
    union { float f; unsigned int i; } v; v.f = f;
    unsigned int x = v.i;
    return (unsigned short)((x + 0x7fffu + ((x >> 16) & 1u)) >> 16);
}

// Kernel 0: convert q (f32) -> bf16 in ws
__global__ __launch_bounds__(256) void conv_q(const float4v* __restrict__ in,
                                              short4v* __restrict__ outp, int n4) {
    int idx = blockIdx.x * 256 + threadIdx.x;
    if (idx < n4) {
        float4v v = in[idx];
        short4v s;
        s[0] = (short)f2bf(v[0]); s[1] = (short)f2bf(v[1]);
        s[2] = (short)f2bf(v[2]); s[3] = (short)f2bf(v[3]);
        outp[idx] = s;
    }
}

// Kernel 1: rk[m, o] = sum_m' r[m, m'] * W_r[o, m']  (f32 in, bf16 out, K=1024)
__global__ __launch_bounds__(256) void rk_gemm(const float* __restrict__ r,
                                               const float* __restrict__ wr,
                                               unsigned short* __restrict__ rk) {
    int tid = threadIdx.x;
    int w = tid >> 6, lane = tid & 63, li = lane & 15, quad = lane >> 4;
    int m0 = blockIdx.x * 64 + (w & 1) * 32;
    int n0 = blockIdx.y * 64 + (w >> 1) * 32;
    float4v acc[2][2] = {};
    for (int kk = 0; kk < DMODEL; kk += 32) {
        short8 a[2], b[2];
#pragma unroll
        for (int t = 0; t < 2; ++t) {
            const float* ap = r  + (size_t)(m0 + t*16 + li) * DMODEL + kk + quad*8;
            const float* bp = wr + (size_t)(n0 + t*16 + li) * DMODEL + kk + quad*8;
            float4v a0 = *(const float4v*)ap, a1 = *(const float4v*)(ap + 4);
            float4v b0 = *(const float4v*)bp, b1 = *(const float4v*)(bp + 4);
#pragma unroll
            for (int j = 0; j < 4; ++j) {
                a[t][j]   = (short)f2bf(a0[j]); a[t][j+4] = (short)f2bf(a1[j]);
                b[t][j]   = (short)f2bf(b0[j]); b[t][j+4] = (short)f2bf(b1[j]);
            }
        }
#pragma unroll
        for (int mi = 0; mi < 2; ++mi)
#pragma unroll
            for (int ni = 0; ni < 2; ++ni)
                acc[mi][ni] = __builtin_amdgcn_mfma_f32_16x16x32_bf16(a[mi], b[ni], acc[mi][ni], 0, 0, 0);
    }
#pragma unroll
    for (int mi = 0; mi < 2; ++mi)
#pragma unroll
        for (int ni = 0; ni < 2; ++ni)
#pragma unroll
            for (int rr = 0; rr < 4; ++rr) {
                int m = m0 + mi*16 + quad*4 + rr;
                int n = n0 + ni*16 + li;
                rk[(size_t)m * DMODEL + n] = f2bf(acc[mi][ni][rr]);
            }
}

// Kernel 2: C[j,n] = sum_{b,d} r_w_bias[n,d] * k[j,b,n,d]   (f32)
__global__ __launch_bounds__(256) void c_kernel(const float* __restrict__ k,
                                                const float* __restrict__ bw,
                                                float* __restrict__ C) {
    int idx = blockIdx.x * 256 + threadIdx.x;  // 2048*16
    int j = idx >> 4, n = idx & 15;
    float acc = 0.f;
#pragma unroll
    for (int b = 0; b < BSZ; ++b) {
        const float4v* kp = (const float4v*)(k + (size_t)j * 4096 + b * 1024 + n * 64);
        const float4v* wp = (const float4v*)(bw + n * 64);
#pragma unroll
        for (int d4 = 0; d4 < 16; ++d4) {
            float4v kv = kp[d4], wv = wp[d4];
            acc += wv[0]*kv[0] + wv[1]*kv[1] + wv[2]*kv[2] + wv[3]*kv[3];
        }
    }
    C[idx] = acc;
}

// Kernel 3: D[kpos,n] = sum_d r_r_bias[n,d] * rk_bf16[kpos, n*64+d]
__global__ __launch_bounds__(256) void d_kernel(const unsigned short* __restrict__ rk,
                                                const float* __restrict__ br,
                                                float* __restrict__ D) {
    int idx = blockIdx.x * 256 + threadIdx.x;  // 2048*16
    int kpos = idx >> 4, n = idx & 15;
    const unsigned short* rp = rk + (size_t)kpos * DMODEL + n * 64;
    float acc = 0.f;
#pragma unroll
    for (int d = 0; d < 64; ++d)
        acc += br[n*64 + d] * bf2f(rp[d]);
    D[idx] = acc;
}

// Kernel 4: rel-shift zero-pad cells get C only. f = i*2049 + 1025, i in [0,1023)
__global__ __launch_bounds__(256) void gap_kernel(const float* __restrict__ C,
                                                  float* __restrict__ out) {
    int idx = blockIdx.x * 256 + threadIdx.x;
    if (idx >= 1023 * 64) return;
    int i = idx >> 6, c = idx & 63;
    int f = i * RP1 + 1025;
    int j = f & 2047;
    int n = c & 15;
    __builtin_nontemporal_store(C[j * 16 + n], out + (size_t)f * 64 + c);
}

// Kernel 5: main. Tile 16i x 16k x 64c. out[f*64+c] = B[i,k,c] + D[k,n] + C[f&2047, n]
// f = i*2049 + k - 1023 (drop f<0). LDS-transposed for coalesced dwordx4 stores.
// XCD-grouped block order: each XCD owns 8 consecutive i-tiles (1 MB q slice fits
// its private 4 MiB L2), iterates kb-major. Depth-1 register prefetch of next-n
// operands so MFMA never waits on this iteration's loads. Non-temporal output
// stores so the 512 MiB write stream doesn't evict the q/rk working set from L2.
__global__ __launch_bounds__(256) void main_kernel(const unsigned short* __restrict__ qb,
                                                   const unsigned short* __restrict__ rkb,
                                                   const float* __restrict__ Cp,
                                                   const float* __restrict__ Dp,
                                                   float* __restrict__ out) {
    __shared__ float lds[16 * 16 * 64];  // [iloc][kloc][c^swz], 64 KB
    int tid = threadIdx.x;
    int w = tid >> 6, lane = tid & 63, li = lane & 15, quad = lane >> 4;

    // XCD-grouped remap: 8 XCDs x 8 i-tiles x 128 kb-tiles (bijective over 8192)
    int bid = blockIdx.x;
    int xcd = bid & 7;
    int r2 = bid >> 3;
    int i_tile = xcd * 8 + (r2 & 7);
    int kb = (r2 >> 3) * 16;
    int i0 = i_tile * 16;

    int k = kb + li;
    const unsigned short* qbase = qb + (size_t)(i0 + li) * 4096 + w * 16 * 64 + quad * 8;
    const unsigned short* rbase = rkb + (size_t)k * DMODEL + quad * 8;

    // C row bases: j = (i0 + iloc + k - 1023) & 2047 is n-invariant (2049 == 1 mod 2048)
    const float* crow[4];
#pragma unroll
    for (int rr = 0; rr < 4; ++rr)
        crow[rr] = Cp + (((i0 + quad * 4 + rr + k - 1023) & 2047) << 4);
    const float* drow = Dp + k * 16;

    // Prologue loads for n = 0
    short8 a0 = *(const short8*)(qbase);
    short8 a1 = *(const short8*)(qbase + 32);
    short8 b0 = *(const short8*)(rbase);
    short8 b1 = *(const short8*)(rbase + 32);
    float dv = drow[0];
    float cv0 = crow[0][0], cv1 = crow[1][0], cv2 = crow[2][0], cv3 = crow[3][0];

    for (int n = 0; n < 16; ++n) {
        short8 na0, na1, nb0, nb1;
        float ndv, ncv0, ncv1, ncv2, ncv3;
        if (n < 15) {  // prefetch next iteration's operands
            const unsigned short* qn = qbase + (n + 1) * 64;
            const unsigned short* rn = rbase + (n + 1) * 64;
            na0 = *(const short8*)qn;  na1 = *(const short8*)(qn + 32);
            nb0 = *(const short8*)rn;  nb1 = *(const short8*)(rn + 32);
            ndv = drow[n + 1];
            ncv0 = crow[0][n + 1]; ncv1 = crow[1][n + 1];
            ncv2 = crow[2][n + 1]; ncv3 = crow[3][n + 1];
        }
        float4v acc = {0.f, 0.f, 0.f, 0.f};
        acc = __builtin_amdgcn_mfma_f32_16x16x32_bf16(a0, b0, acc, 0, 0, 0);
        acc = __builtin_amdgcn_mfma_f32_16x16x32_bf16(a1, b1, acc, 0, 0, 0);
        int c = w * 16 + n;
        int csw = c ^ ((li & 7) << 2) ^ quad;  // bank swizzle: 2-way is free
        lds[((quad * 4 + 0) * 16 + li) * 64 + csw] = (acc[0] + dv) + cv0;
        lds[((quad * 4 + 1) * 16 + li) * 64 + csw] = (acc[1] + dv) + cv1;
        lds[((quad * 4 + 2) * 16 + li) * 64 + csw] = (acc[2] + dv) + cv2;
        lds[((quad * 4 + 3) * 16 + li) * 64 + csw] = (acc[3] + dv) + cv3;
        if (n < 15) {
            a0 = na0; a1 = na1; b0 = nb0; b1 = nb1;
            dv = ndv; cv0 = ncv0; cv1 = ncv1; cv2 = ncv2; cv3 = ncv3;
        }
    }
    __syncthreads();
    // Coalesced stores: per iloc row, 16k x 64c = 1024 contiguous f32 (4 KB)
    int kloc = tid >> 4;        // 0..15
    int c0 = (tid & 15) * 4;    // float4 chunk
    int kx = (kloc & 7) << 2;
#pragma unroll
    for (int il = 0; il < 16; ++il) {
        int f = (i0 + il) * RP1 + kb + kloc - 1023;
        if (f >= 0) {
            int qx = (il >> 2) & 3;
            const float4v L = *(const float4v*)&lds[(il * 16 + kloc) * 64 + (c0 ^ kx)];
            float4v v;
            v[0] = L[0 ^ qx]; v[1] = L[1 ^ qx]; v[2] = L[2 ^ qx]; v[3] = L[3 ^ qx];
            __builtin_nontemporal_store(v, (float4v*)(out + (size_t)f * 64 + c0));
        }
    }
}

extern "C" void kernel_launch(void* const* d_in, const int* in_sizes, int n_in,
                              void* d_out, int out_size, void* d_ws, size_t ws_size,
                              hipStream_t stream) {
    const float* q  = (const float*)d_in[0];  // [1024,4,16,64] f32
    const float* k  = (const float*)d_in[1];  // [2048,4,16,64] f32
    const float* r  = (const float*)d_in[2];  // [2048,1024] f32
    const float* wr = (const float*)d_in[3];  // [1024,1024] f32
    const float* bw = (const float*)d_in[4];  // [16,64] f32
    const float* br = (const float*)d_in[5];  // [16,64] f32
    float* out = (float*)d_out;

    unsigned short* rk = (unsigned short*)d_ws;                           // 4 MB bf16
    unsigned short* qbf = (unsigned short*)((char*)d_ws + (4u << 20));    // 8 MB bf16
    float* C = (float*)((char*)d_ws + (12u << 20));                       // 128 KB f32
    float* D = (float*)((char*)d_ws + (12u << 20) + (128u << 10));        // 128 KB f32

    conv_q<<<4096, 256, 0, stream>>>((const float4v*)q, (short4v*)qbf, QLEN * BSZ * NHEAD * DHEAD / 4);
    rk_gemm<<<dim3(KLEN / 64, DMODEL / 64), 256, 0, stream>>>(r, wr, rk);
    c_kernel<<<(KLEN * NHEAD) / 256, 256, 0, stream>>>(k, bw, C);
    d_kernel<<<(KLEN * NHEAD) / 256, 256, 0, stream>>>(rk, br, D);
    gap_kernel<<<(1023 * 64 + 255) / 256, 256, 0, stream>>>(C, out);
    main_kernel<<<8192, 256, 0, stream>>>(qbf, rk, C, D, out);
}